// Round 15
// baseline (267.918 us; speedup 1.0000x reference)
//
#include <hip/hip_runtime.h>
#include <hip/hip_fp16.h>
#include <stdint.h>

#define NNODES 50000
#define NEDGES 800000
#define NHID 96
#define NCLS 16

// graph build: NC edge-chunks x NR node-ranges; per-block LDS histogram of one
// range (12500 nodes, u8 quad-packed into 3125 u32 words).
#define NC 100
#define NR 4
#define EPB (NEDGES / NC)           // 8000 edges per chunk
#define RNODES (NNODES / NR)        // 12500 nodes per range
#define RWORDS8 (RNODES / 4)        // 3125 packed words (u8 x4)
#define NWORDS8 (NNODES / 4)        // 12500 global packed words
#define SCANB ((NWORDS8 + 255) / 256)              // 49 scan blocks
#define HISTBLKS (NC * NR)                         // 400 hist blocks
#define G96B ((NNODES + 127) / 128)                // 391 gemm96 blocks
#define G96PAD 392                                 // padded to %8==0 for XCD pinning
#define FR 8                                       // fill ranges (XCD-pinned)
#define FRNODES (NNODES / FR)                      // 6250 nodes per fill range
#define FILLB4 (NC * FR)                           // 800 range-fill blocks
#define NDROP4 ((NNODES * NHID / 4 + 255) / 256)   // 4688 drop0 blocks

// ---------- JAX Threefry-2x32 (Random123 20-round, matches jax._src.prng) ----------
__host__ __device__ inline void tf2x32(uint32_t k0, uint32_t k1, uint32_t x0, uint32_t x1,
                                       uint32_t& o0, uint32_t& o1) {
  uint32_t k2 = k0 ^ k1 ^ 0x1BD11BDAu;
#define TFROT(v, r) (((v) << (r)) | ((v) >> (32 - (r))))
#define TFR(r) { x0 += x1; x1 = TFROT(x1, r); x1 ^= x0; }
  x0 += k0; x1 += k1;
  TFR(13) TFR(15) TFR(26) TFR(6)
  x0 += k1; x1 += k2 + 1u;
  TFR(17) TFR(29) TFR(16) TFR(24)
  x0 += k2; x1 += k0 + 2u;
  TFR(13) TFR(15) TFR(26) TFR(6)
  x0 += k0; x1 += k1 + 3u;
  TFR(17) TFR(29) TFR(16) TFR(24)
  x0 += k1; x1 += k2 + 4u;
  TFR(13) TFR(15) TFR(26) TFR(6)
  x0 += k2; x1 += k0 + 5u;
  o0 = x0; o1 = x1;
#undef TFR
#undef TFROT
}

__device__ inline bool keep_bit(uint32_t k0, uint32_t k1, uint32_t j) {
  uint32_t o0, o1;
  tf2x32(k0, k1, 0u, j, o0, o1);
  return (((o0 ^ o1) >> 31) == 0u);   // uniform<0.5 <=> MSB==0
}

// ---------- pass 1: LDS histograms (blocks 0..400) + layer-0 dropout (rest) ----------
// inv_o is folded into csr weights at fill time, so drop0 is X = mask ? feat*2 : 0.
// The dst atomicAdd's return value is the edge's rank within (chunk,node) -> rank8.
// Block 0 zeroes the lookback flags for reduce_scan.
__global__ __launch_bounds__(256) void hist_drop_kernel(
    const int* __restrict__ src, const int* __restrict__ dst,
    uint32_t* __restrict__ slabD, uint32_t* __restrict__ slabS,
    uint8_t* __restrict__ rank8, uint32_t* __restrict__ flags,
    const float* __restrict__ h, float* __restrict__ X,
    uint32_t k0, uint32_t k1) {
  __shared__ uint32_t HD[RWORDS8];
  __shared__ uint32_t HS[RWORDS8];
  const int tid = threadIdx.x, b = blockIdx.x;
  if (b >= HISTBLKS) {
    // ---- drop0 branch: one float4 per thread ----
    int j = ((b - HISTBLKS) * 256 + tid) * 4;
    if (j < NNODES * NHID) {
      float4 hv = *(const float4*)(h + j);
      float4 o;
      o.x = keep_bit(k0, k1, (uint32_t)(j + 0)) ? hv.x * 2.0f : 0.0f;
      o.y = keep_bit(k0, k1, (uint32_t)(j + 1)) ? hv.y * 2.0f : 0.0f;
      o.z = keep_bit(k0, k1, (uint32_t)(j + 2)) ? hv.z * 2.0f : 0.0f;
      o.w = keep_bit(k0, k1, (uint32_t)(j + 3)) ? hv.w * 2.0f : 0.0f;
      *(float4*)(X + j) = o;
    }
    return;
  }
  // ---- hist branch ----
  if (b == 0 && tid < SCANB) flags[tid] = 0;
  const int c = b / NR, r = b - c * NR;
  const int e0 = c * EPB, e1 = e0 + EPB;
  const int nbase = r * RNODES;
  for (int w = tid; w < RWORDS8; w += 256) { HD[w] = 0; HS[w] = 0; }
  __syncthreads();
  int e = e0 + tid;
  for (; e + 768 < e1; e += 1024) {
    int d0 = dst[e] - nbase,       d1 = dst[e + 256] - nbase;
    int d2 = dst[e + 512] - nbase, d3 = dst[e + 768] - nbase;
    int s0 = src[e] - nbase,       s1 = src[e + 256] - nbase;
    int s2 = src[e + 512] - nbase, s3 = src[e + 768] - nbase;
    if ((unsigned)d0 < (unsigned)RNODES) {
      int sh = (d0 & 3) * 8;
      uint32_t old = atomicAdd(&HD[d0 >> 2], 1u << sh);
      rank8[e] = (uint8_t)((old >> sh) & 0xFFu);
    }
    if ((unsigned)d1 < (unsigned)RNODES) {
      int sh = (d1 & 3) * 8;
      uint32_t old = atomicAdd(&HD[d1 >> 2], 1u << sh);
      rank8[e + 256] = (uint8_t)((old >> sh) & 0xFFu);
    }
    if ((unsigned)d2 < (unsigned)RNODES) {
      int sh = (d2 & 3) * 8;
      uint32_t old = atomicAdd(&HD[d2 >> 2], 1u << sh);
      rank8[e + 512] = (uint8_t)((old >> sh) & 0xFFu);
    }
    if ((unsigned)d3 < (unsigned)RNODES) {
      int sh = (d3 & 3) * 8;
      uint32_t old = atomicAdd(&HD[d3 >> 2], 1u << sh);
      rank8[e + 768] = (uint8_t)((old >> sh) & 0xFFu);
    }
    if ((unsigned)s0 < (unsigned)RNODES) atomicAdd(&HS[s0 >> 2], 1u << ((s0 & 3) * 8));
    if ((unsigned)s1 < (unsigned)RNODES) atomicAdd(&HS[s1 >> 2], 1u << ((s1 & 3) * 8));
    if ((unsigned)s2 < (unsigned)RNODES) atomicAdd(&HS[s2 >> 2], 1u << ((s2 & 3) * 8));
    if ((unsigned)s3 < (unsigned)RNODES) atomicAdd(&HS[s3 >> 2], 1u << ((s3 & 3) * 8));
  }
  for (; e < e1; e += 256) {
    int d = dst[e] - nbase;
    if ((unsigned)d < (unsigned)RNODES) {
      int sh = (d & 3) * 8;
      uint32_t old = atomicAdd(&HD[d >> 2], 1u << sh);
      rank8[e] = (uint8_t)((old >> sh) & 0xFFu);
    }
    int s = src[e] - nbase;
    if ((unsigned)s < (unsigned)RNODES) atomicAdd(&HS[s >> 2], 1u << ((s & 3) * 8));
  }
  __syncthreads();
  uint32_t* dpD = slabD + (size_t)b * RWORDS8;
  uint32_t* dpS = slabS + (size_t)b * RWORDS8;
  for (int w = tid; w < RWORDS8; w += 256) { dpD[w] = HD[w]; dpS[w] = HS[w]; }
}

// ---------- fused reduce + rel-base + inv + full exclusive scan -> row_ptr ----------
// packed-byte running sums (per-node degree < 256 so no cross-byte carry).
// Decoupled lookback over 49 blocks (all co-resident): flags[b] = 0x80000000|total.
__global__ __launch_bounds__(256) void reduce_scan_kernel(
    const uint32_t* __restrict__ slabD, const uint32_t* __restrict__ slabS,
    float* __restrict__ inv_o, float* __restrict__ inv_i,
    uint32_t* __restrict__ rel8, int* __restrict__ row_ptr,
    uint32_t* __restrict__ flags) {
  __shared__ int lds[256];
  __shared__ int base_s;
  const int tid = threadIdx.x, b = blockIdx.x;
  const int gw = b * 256 + tid;
  uint32_t runD = 0, runS = 0;
  int n0 = 0;
  if (gw < NWORDS8) {
    int r = gw / RWORDS8, lw = gw - r * RWORDS8;
    n0 = r * RNODES + 4 * lw;
#pragma unroll 4
    for (int c = 0; c < NC; ++c) {
      rel8[(size_t)c * NWORDS8 + gw] = runD;
      runD += slabD[(size_t)(c * NR + r) * RWORDS8 + lw];
      runS += slabS[(size_t)(c * NR + r) * RWORDS8 + lw];
    }
  }
  const int d0 = runD & 0xFF, d1 = (runD >> 8) & 0xFF,
            d2 = (runD >> 16) & 0xFF, d3 = runD >> 24;
  const int tsum = d0 + d1 + d2 + d3;
  lds[tid] = tsum;
  __syncthreads();
  for (int off = 1; off < 256; off <<= 1) {
    int t = (tid >= off) ? lds[tid - off] : 0;
    __syncthreads();
    lds[tid] += t;
    __syncthreads();
  }
  const int incl = lds[tid];
  if (tid == 255) atomicExch(&flags[b], 0x80000000u | (uint32_t)lds[255]);
  if (tid < 64) {
    uint32_t part = 0;
    if (tid < b) {
      uint32_t v;
      do { v = atomicAdd(&flags[tid], 0u); } while (!(v & 0x80000000u));
      part = v & 0x7FFFFFFFu;
    }
#pragma unroll
    for (int off = 32; off > 0; off >>= 1)
      part += __shfl_down((unsigned)part, off, 64);
    if (tid == 0) base_s = (int)part;
  }
  __syncthreads();
  const int base = base_s;
  if (gw < NWORDS8) {
    int excl = base + incl - tsum;   // exclusive prefix for node n0
    *(int4*)(row_ptr + n0) = make_int4(excl, excl + d0, excl + d0 + d1, excl + d0 + d1 + d2);
    *(float4*)(inv_i + n0) = make_float4(
        rsqrtf(fmaxf((float)d0, 1.0f)), rsqrtf(fmaxf((float)d1, 1.0f)),
        rsqrtf(fmaxf((float)d2, 1.0f)), rsqrtf(fmaxf((float)d3, 1.0f)));
    int o0 = runS & 0xFF, o1 = (runS >> 8) & 0xFF, o2 = (runS >> 16) & 0xFF, o3 = runS >> 24;
    *(float4*)(inv_o + n0) = make_float4(
        rsqrtf(fmaxf((float)o0, 1.0f)), rsqrtf(fmaxf((float)o1, 1.0f)),
        rsqrtf(fmaxf((float)o2, 1.0f)), rsqrtf(fmaxf((float)o3, 1.0f)));
    if (gw == NWORDS8 - 1) row_ptr[NNODES] = NEDGES;
  }
}

// ---------- fused: gemm96 layer 0 (blocks 0..392) + XCD-pinned range fill ----------
// GEMM FIRST (all compute resident at t=0), then 800 fill blocks (chunk c,
// dst-range r). Gemm section padded to 392 (%8==0) so fill block i has
// blockIdx%8 == i%8 == r: every csr write for range r's ~0.8MB region comes
// from ONE XCD -> 64B lines collect all their 16 entries in that L2 before
// writeback (fixes the 12x WRITE amplification measured in round 12).
__global__ __launch_bounds__(256) void fill_gemm_kernel(
    const int* __restrict__ src, const int* __restrict__ dst, const float* __restrict__ ew,
    const uint8_t* __restrict__ rank8, const uint32_t* __restrict__ rel8,
    const int* __restrict__ row_ptr, const float* __restrict__ inv_o,
    uint32_t* __restrict__ csr,
    const float* __restrict__ X, const float* __restrict__ W, __half* __restrict__ Yh) {
  __shared__ float Wl[96 * 96];
  const int tid = threadIdx.x, b = blockIdx.x;
  if (b >= G96PAD) {
    // ---- fill branch: (chunk c, range r), r == blockIdx % 8 == XCD ----
    const int i = b - G96PAD;          // 0..799
    const int r = i & 7;               // dst range, XCD-pinned
    const int c = i >> 3;              // chunk 0..99
    const int e0 = c * EPB, e1 = e0 + EPB;
    const int lo = r * FRNODES, hi = lo + FRNODES;
    const uint32_t* rel = rel8 + (size_t)c * NWORDS8;
    for (int e = e0 + tid; e < e1; e += 256) {
      int d = dst[e];
      if (d >= lo && d < hi) {
        int s = src[e];
        float w = ew[e] * inv_o[s];    // fold D_out^-1/2 into the edge weight
        int rk = (int)rank8[e];
        int sh = (d & 3) * 8;
        int rel_v = (int)((rel[d >> 2] >> sh) & 0xFFu);
        int pos = row_ptr[d] + rel_v + rk;
        uint32_t v = ((uint32_t)s << 16) | (uint32_t)__half_as_ushort(__float2half_rn(w));
        if ((unsigned)pos < (unsigned)NEDGES) csr[pos] = v;
      }
    }
    return;
  }
  // ---- gemm96 branch (layer 0); block 391 is padding (row0 >= NNODES, no stores) ----
  const int gb = b;
  {
    const float4* Wg = (const float4*)W;
    float4* Ws = (float4*)Wl;
#pragma unroll
    for (int i = 0; i < 9; ++i)
      Ws[tid + i * 256] = Wg[tid + i * 256];
  }
  __syncthreads();

  const int cg = tid & 7;
  const int rq = tid >> 3;
  const int row0 = gb * 128 + rq * 4;
  const int c0 = cg * 12;

  float acc[4][12];
#pragma unroll
  for (int r = 0; r < 4; ++r)
#pragma unroll
    for (int c = 0; c < 12; ++c) acc[r][c] = 0.f;

  const float* xr[4];
#pragma unroll
  for (int r = 0; r < 4; ++r) {
    int rr = row0 + r; if (rr > NNODES - 1) rr = NNODES - 1;
    xr[r] = X + (size_t)rr * 96;
  }

  for (int k = 0; k < 96; k += 4) {
    float4 x4[4];
#pragma unroll
    for (int r = 0; r < 4; ++r) x4[r] = *(const float4*)(xr[r] + k);
#pragma unroll
    for (int kk = 0; kk < 4; ++kk) {
      const float4* wp = (const float4*)(Wl + (k + kk) * 96 + c0);
      float4 w0 = wp[0], w1 = wp[1], w2 = wp[2];
      float xv[4] = { (&x4[0].x)[kk], (&x4[1].x)[kk], (&x4[2].x)[kk], (&x4[3].x)[kk] };
#pragma unroll
      for (int r = 0; r < 4; ++r) {
        acc[r][0]  += xv[r] * w0.x; acc[r][1]  += xv[r] * w0.y;
        acc[r][2]  += xv[r] * w0.z; acc[r][3]  += xv[r] * w0.w;
        acc[r][4]  += xv[r] * w1.x; acc[r][5]  += xv[r] * w1.y;
        acc[r][6]  += xv[r] * w1.z; acc[r][7]  += xv[r] * w1.w;
        acc[r][8]  += xv[r] * w2.x; acc[r][9]  += xv[r] * w2.y;
        acc[r][10] += xv[r] * w2.z; acc[r][11] += xv[r] * w2.w;
      }
    }
  }

#pragma unroll
  for (int r = 0; r < 4; ++r) {
    int rr = row0 + r;
    if (rr < NNODES) {
      __half2* hp = (__half2*)(Yh + (size_t)rr * 96 + c0);
#pragma unroll
      for (int c = 0; c < 6; ++c)
        hp[c] = __floats2half2_rn(acc[r][2 * c], acc[r][2 * c + 1]);
    }
  }
}

// ---------- GEMM96 (standalone, layer 1) ----------
__global__ __launch_bounds__(256) void gemm96_kernel(
    const float* __restrict__ X, const float* __restrict__ W, __half* __restrict__ Yh) {
  __shared__ float Wl[96 * 96];
  const int tid = threadIdx.x;
  {
    const float4* Wg = (const float4*)W;
    float4* Ws = (float4*)Wl;
#pragma unroll
    for (int i = 0; i < 9; ++i)
      Ws[tid + i * 256] = Wg[tid + i * 256];
  }
  __syncthreads();

  const int cg = tid & 7;
  const int rq = tid >> 3;
  const int row0 = blockIdx.x * 128 + rq * 4;
  const int c0 = cg * 12;

  float acc[4][12];
#pragma unroll
  for (int r = 0; r < 4; ++r)
#pragma unroll
    for (int c = 0; c < 12; ++c) acc[r][c] = 0.f;

  const float* xr[4];
#pragma unroll
  for (int r = 0; r < 4; ++r) {
    int rr = row0 + r; if (rr > NNODES - 1) rr = NNODES - 1;
    xr[r] = X + (size_t)rr * 96;
  }

  for (int k = 0; k < 96; k += 4) {
    float4 x4[4];
#pragma unroll
    for (int r = 0; r < 4; ++r) x4[r] = *(const float4*)(xr[r] + k);
#pragma unroll
    for (int kk = 0; kk < 4; ++kk) {
      const float4* wp = (const float4*)(Wl + (k + kk) * 96 + c0);
      float4 w0 = wp[0], w1 = wp[1], w2 = wp[2];
      float xv[4] = { (&x4[0].x)[kk], (&x4[1].x)[kk], (&x4[2].x)[kk], (&x4[3].x)[kk] };
#pragma unroll
      for (int r = 0; r < 4; ++r) {
        acc[r][0]  += xv[r] * w0.x; acc[r][1]  += xv[r] * w0.y;
        acc[r][2]  += xv[r] * w0.z; acc[r][3]  += xv[r] * w0.w;
        acc[r][4]  += xv[r] * w1.x; acc[r][5]  += xv[r] * w1.y;
        acc[r][6]  += xv[r] * w1.z; acc[r][7]  += xv[r] * w1.w;
        acc[r][8]  += xv[r] * w2.x; acc[r][9]  += xv[r] * w2.y;
        acc[r][10] += xv[r] * w2.z; acc[r][11] += xv[r] * w2.w;
      }
    }
  }

#pragma unroll
  for (int r = 0; r < 4; ++r) {
    int rr = row0 + r;
    if (rr < NNODES) {
      __half2* hp = (__half2*)(Yh + (size_t)rr * 96 + c0);
#pragma unroll
      for (int c = 0; c < 6; ++c)
        hp[c] = __floats2half2_rn(acc[r][2 * c], acc[r][2 * c + 1]);
    }
  }
}

// ---------- GEMM16: Y2h[N,16](fp16) = X[N,96] @ W[96,16], LDS-staged W ----------
__global__ __launch_bounds__(256) void gemm16_kernel(
    const float* __restrict__ X, const float* __restrict__ W, __half* __restrict__ Y2h) {
  __shared__ float Wl[96 * 16];
  const int tid = threadIdx.x;
  {
    const float4* Wg = (const float4*)W;
    float4* Ws = (float4*)Wl;
    for (int i = tid; i < 384; i += 256) Ws[i] = Wg[i];
  }
  __syncthreads();

  const int row0 = blockIdx.x * 512 + tid * 2;
  const float* xr[2];
#pragma unroll
  for (int r = 0; r < 2; ++r) {
    int rr = row0 + r; if (rr > NNODES - 1) rr = NNODES - 1;
    xr[r] = X + (size_t)rr * 96;
  }

  float acc[2][16];
#pragma unroll
  for (int r = 0; r < 2; ++r)
#pragma unroll
    for (int c = 0; c < 16; ++c) acc[r][c] = 0.f;

  for (int k = 0; k < 96; k += 4) {
    float4 x4[2];
#pragma unroll
    for (int r = 0; r < 2; ++r) x4[r] = *(const float4*)(xr[r] + k);
#pragma unroll
    for (int kk = 0; kk < 4; ++kk) {
      const float4* wp = (const float4*)(Wl + (k + kk) * 16);
      float4 w0 = wp[0], w1 = wp[1], w2 = wp[2], w3 = wp[3];
#pragma unroll
      for (int r = 0; r < 2; ++r) {
        float xv = (&x4[r].x)[kk];
        acc[r][0]  += xv * w0.x; acc[r][1]  += xv * w0.y;
        acc[r][2]  += xv * w0.z; acc[r][3]  += xv * w0.w;
        acc[r][4]  += xv * w1.x; acc[r][5]  += xv * w1.y;
        acc[r][6]  += xv * w1.z; acc[r][7]  += xv * w1.w;
        acc[r][8]  += xv * w2.x; acc[r][9]  += xv * w2.y;
        acc[r][10] += xv * w2.z; acc[r][11] += xv * w2.w;
        acc[r][12] += xv * w3.x; acc[r][13] += xv * w3.y;
        acc[r][14] += xv * w3.z; acc[r][15] += xv * w3.w;
      }
    }
  }

#pragma unroll
  for (int r = 0; r < 2; ++r) {
    int rr = row0 + r;
    if (rr < NNODES) {
      __half2* hp = (__half2*)(Y2h + (size_t)rr * 16);
#pragma unroll
      for (int c = 0; c < 8; ++c)
        hp[c] = __floats2half2_rn(acc[r][2 * c], acc[r][2 * c + 1]);
    }
  }
}

// accumulate one uint2 (4 fp16) into acc[0..3] with weight wt
#define ACC4(u0, wt) { \
  float2 g0 = __half22float2(*(__half2*)&u0.x); \
  float2 g1 = __half22float2(*(__half2*)&u0.y); \
  acc[0] += g0.x * wt; acc[1] += g0.y * wt; \
  acc[2] += g1.x * wt; acc[3] += g1.y * wt; }

// ---------- CSR gather (fp16 Y) + inv_in*bias + ReLU + dropout*2 ----------
// 24 threads/node, 4-dim (one uint2) chunks: 1.2M threads (proven best shape;
// TLP saturates here -- resident-thread cap is the binding constraint).
__global__ __launch_bounds__(256) void gather96_drop_kernel(
    const __half* __restrict__ Yh, const uint32_t* __restrict__ csr,
    const int* __restrict__ row_ptr, const float* __restrict__ inv_in,
    const float* __restrict__ bias,
    float* __restrict__ Xn, uint32_t k0, uint32_t k1) {
  int tid = blockIdx.x * 256 + threadIdx.x;
  int n = tid / 24;
  int q = tid - n * 24;        // 4-dim chunk within the 96-dim row
  if (n >= NNODES) return;
  int beg = row_ptr[n], end = row_ptr[n + 1];
  float acc[4];
#pragma unroll
  for (int i = 0; i < 4; ++i) acc[i] = 0.f;

  int p = beg;
  for (; p + 8 <= end; p += 8) {
    uint32_t pw[8];
#pragma unroll
    for (int i = 0; i < 8; ++i) pw[i] = csr[p + i];
    float wv[8];
    uint2 u[8];
#pragma unroll
    for (int i = 0; i < 8; ++i) {
      int s = (int)(pw[i] >> 16); if (s >= NNODES) s = 0;
      wv[i] = __half2float(__ushort_as_half((unsigned short)(pw[i] & 0xFFFFu)));
      u[i] = *(const uint2*)(Yh + (size_t)s * 96 + q * 4);
    }
#pragma unroll
    for (int i = 0; i < 8; ++i) { ACC4(u[i], wv[i]) }
  }
  for (; p + 2 <= end; p += 2) {
    uint32_t pa = csr[p], pb = csr[p + 1];
    int s0 = pa >> 16, s1 = pb >> 16;
    if (s0 >= NNODES) s0 = 0;
    if (s1 >= NNODES) s1 = 0;
    float w0 = __half2float(__ushort_as_half((unsigned short)(pa & 0xFFFFu)));
    float w1 = __half2float(__ushort_as_half((unsigned short)(pb & 0xFFFFu)));
    uint2 a0 = *(const uint2*)(Yh + (size_t)s0 * 96 + q * 4);
    uint2 b0 = *(const uint2*)(Yh + (size_t)s1 * 96 + q * 4);
    ACC4(a0, w0)
    ACC4(b0, w1)
  }
  if (p < end) {
    uint32_t pa = csr[p];
    int s0 = pa >> 16;
    if (s0 >= NNODES) s0 = 0;
    float w0 = __half2float(__ushort_as_half((unsigned short)(pa & 0xFFFFu)));
    uint2 a0 = *(const uint2*)(Yh + (size_t)s0 * 96 + q * 4);
    ACC4(a0, w0)
  }

  float iv = inv_in[n];
  const float* bp = bias + q * 4;
  float o[4];
#pragma unroll
  for (int i = 0; i < 4; ++i)
    o[i] = fmaxf(acc[i] * iv + bp[i], 0.f) * 2.0f;   // dropout 1/(1-p) only
  uint32_t jb = (uint32_t)(n * 96 + q * 4);
#pragma unroll
  for (int i = 0; i < 4; ++i)
    o[i] = keep_bit(k0, k1, jb + i) ? o[i] : 0.f;
  float* xp = Xn + (size_t)n * 96 + q * 4;
  *(float4*)xp = make_float4(o[0], o[1], o[2], o[3]);
}

// ---------- layer 2: CSR gather (fp16 Y2) + bias + log_softmax ----------
// 4 threads/node (4 dims each, one uint2/edge); softmax max/sum combined across
// the 4-lane group via shfl_xor(1)+shfl_xor(2).
__global__ __launch_bounds__(256) void gather16_lsm_kernel(
    const __half* __restrict__ Y2h, const uint32_t* __restrict__ csr,
    const int* __restrict__ row_ptr, const float* __restrict__ inv_in,
    const float* __restrict__ b2, float* __restrict__ out) {
  int t = blockIdx.x * 256 + threadIdx.x;
  int n = t >> 2;
  int q = t & 3;              // 4-dim quarter of the 16-dim row
  if (n >= NNODES) return;
  int beg = row_ptr[n], end = row_ptr[n + 1];
  float acc[4];
#pragma unroll
  for (int i = 0; i < 4; ++i) acc[i] = 0.f;

  int p = beg;
  for (; p + 4 <= end; p += 4) {
    uint32_t pa = csr[p], pb = csr[p + 1], pc = csr[p + 2], pd = csr[p + 3];
    int sa = pa >> 16, sb = pb >> 16, sc_ = pc >> 16, sd = pd >> 16;
    if (sa >= NNODES) sa = 0;
    if (sb >= NNODES) sb = 0;
    if (sc_ >= NNODES) sc_ = 0;
    if (sd >= NNODES) sd = 0;
    float wa = __half2float(__ushort_as_half((unsigned short)(pa & 0xFFFFu)));
    float wb = __half2float(__ushort_as_half((unsigned short)(pb & 0xFFFFu)));
    float wc = __half2float(__ushort_as_half((unsigned short)(pc & 0xFFFFu)));
    float wd = __half2float(__ushort_as_half((unsigned short)(pd & 0xFFFFu)));
    uint2 a0 = *(const uint2*)(Y2h + (size_t)sa * 16 + q * 4);
    uint2 b0 = *(const uint2*)(Y2h + (size_t)sb * 16 + q * 4);
    uint2 c0 = *(const uint2*)(Y2h + (size_t)sc_ * 16 + q * 4);
    uint2 d0 = *(const uint2*)(Y2h + (size_t)sd * 16 + q * 4);
    ACC4(a0, wa) ACC4(b0, wb) ACC4(c0, wc) ACC4(d0, wd)
  }
  for (; p + 2 <= end; p += 2) {
    uint32_t pa = csr[p], pb = csr[p + 1];
    int sa = pa >> 16, sb = pb >> 16;
    if (sa >= NNODES) sa = 0;
    if (sb >= NNODES) sb = 0;
    float wa = __half2float(__ushort_as_half((unsigned short)(pa & 0xFFFFu)));
    float wb = __half2float(__ushort_as_half((unsigned short)(pb & 0xFFFFu)));
    uint2 a0 = *(const uint2*)(Y2h + (size_t)sa * 16 + q * 4);
    uint2 b0 = *(const uint2*)(Y2h + (size_t)sb * 16 + q * 4);
    ACC4(a0, wa) ACC4(b0, wb)
  }
  if (p < end) {
    uint32_t pa = csr[p];
    int sa = pa >> 16;
    if (sa >= NNODES) sa = 0;
    float wa = __half2float(__ushort_as_half((unsigned short)(pa & 0xFFFFu)));
    uint2 a0 = *(const uint2*)(Y2h + (size_t)sa * 16 + q * 4);
    ACC4(a0, wa)
  }

  float iv = inv_in[n];
  float v[4];
#pragma unroll
  for (int i = 0; i < 4; ++i) v[i] = acc[i] * iv + b2[q * 4 + i];
  float m = v[0];
#pragma unroll
  for (int i = 1; i < 4; i++) m = fmaxf(m, v[i]);
  m = fmaxf(m, __shfl_xor(m, 1));       // 4-lane group shares node n
  m = fmaxf(m, __shfl_xor(m, 2));
  float s = 0.f;
#pragma unroll
  for (int i = 0; i < 4; i++) s += expf(v[i] - m);
  s += __shfl_xor(s, 1);
  s += __shfl_xor(s, 2);
  float ls = logf(s);
  float* orow = out + (size_t)n * 16 + q * 4;
  *(float4*)orow = make_float4(v[0] - m - ls, v[1] - m - ls, v[2] - m - ls, v[3] - m - ls);
}

extern "C" void kernel_launch(void* const* d_in, const int* in_sizes, int n_in,
                              void* d_out, int out_size, void* d_ws, size_t ws_size,
                              hipStream_t stream) {
  const float* feat = (const float*)d_in[0];
  const float* ew   = (const float*)d_in[1];
  const int*   src  = (const int*)d_in[2];
  const int*   dst  = (const int*)d_in[3];
  const float* W0   = (const float*)d_in[4];
  const float* b0   = (const float*)d_in[5];
  const float* W1   = (const float*)d_in[6];
  const float* b1   = (const float*)d_in[7];
  const float* W2   = (const float*)d_in[8];
  const float* b2   = (const float*)d_in[9];
  float* out = (float*)d_out;

  char* base = (char*)d_ws;
  size_t off = 0;
  auto take = [&](size_t nbytes) {
    void* q = base + off;
    off += (nbytes + 255) & ~(size_t)255;
    return q;
  };
  uint32_t* flags   = (uint32_t*)take((size_t)SCANB * 4);
  int*      row_ptr = (int*)take((size_t)(NNODES + 1) * 4);
  float*    inv_o   = (float*)take((size_t)NNODES * 4);
  float*    inv_i   = (float*)take((size_t)NNODES * 4);
  uint32_t* slabD   = (uint32_t*)take((size_t)NC * NR * RWORDS8 * 4);  // 5 MB
  uint32_t* slabS   = (uint32_t*)take((size_t)NC * NR * RWORDS8 * 4);  // 5 MB
  uint32_t* rel8    = (uint32_t*)take((size_t)NC * NWORDS8 * 4);       // 5 MB
  uint8_t*  rank8   = (uint8_t*)take((size_t)NEDGES);                  // 0.8 MB
  uint32_t* csr     = (uint32_t*)take((size_t)NEDGES * 4);
  float*    X       = (float*)take((size_t)NNODES * NHID * 4);
  __half*   Yh      = (__half*)take((size_t)NNODES * NHID * 2);
  __half*   Y2h     = (__half*)take((size_t)NNODES * NCLS * 2);
  (void)ws_size; (void)in_sizes; (void)n_in; (void)out_size;

  uint32_t k[3][2];
  for (uint32_t i = 0; i < 3; i++) tf2x32(0u, 42u, 0u, i, k[i][0], k[i][1]);

  // graph build: hist (+drop0 co-scheduled), scan, then gemm96-L0||range-fill
  hist_drop_kernel<<<HISTBLKS + NDROP4, 256, 0, stream>>>(
      src, dst, slabD, slabS, rank8, flags, feat, X, k[0][0], k[0][1]);
  reduce_scan_kernel<<<SCANB, 256, 0, stream>>>(slabD, slabS, inv_o, inv_i, rel8, row_ptr, flags);
  fill_gemm_kernel<<<G96PAD + FILLB4, 256, 0, stream>>>(
      src, dst, ew, rank8, rel8, row_ptr, inv_o, csr, X, W0, Yh);

  const int G16  = (NNODES + 511) / 512;        // 98
  const int GGD  = (NNODES * 24 + 255) / 256;   // 4688
  const int GLSM = (NNODES * 4 + 255) / 256;    // 782

  // layer 0 gather
  gather96_drop_kernel<<<GGD, 256, 0, stream>>>(Yh, csr, row_ptr, inv_i, b0, X, k[1][0], k[1][1]);
  // layer 1
  gemm96_kernel<<<G96B, 256, 0, stream>>>(X, W1, Yh);
  gather96_drop_kernel<<<GGD, 256, 0, stream>>>(Yh, csr, row_ptr, inv_i, b1, X, k[2][0], k[2][1]);
  // layer 2
  gemm16_kernel<<<G16, 256, 0, stream>>>(X, W2, Y2h);
  gather16_lsm_kernel<<<GLSM, 256, 0, stream>>>(Y2h, csr, row_ptr, inv_i, b2, out);
}

// Round 16
// 249.350 us; speedup vs baseline: 1.0745x; 1.0745x over previous
//
#include <hip/hip_runtime.h>
#include <hip/hip_fp16.h>
#include <stdint.h>

#define NNODES 50000
#define NEDGES 800000
#define NHID 96
#define NCLS 16

// graph build: NC edge-chunks x NR node-ranges; per-block LDS histogram of one
// range (12500 nodes, u8 quad-packed into 3125 u32 words).
#define NC 100
#define NR 4
#define EPB (NEDGES / NC)           // 8000 edges per chunk
#define RNODES (NNODES / NR)        // 12500 nodes per range
#define RWORDS8 (RNODES / 4)        // 3125 packed words (u8 x4)
#define NWORDS8 (NNODES / 4)        // 12500 global packed words
#define SCANB ((NWORDS8 + 255) / 256)              // 49 scan blocks
#define HISTBLKS (NC * NR)                         // 400 hist blocks
#define FEPT8 8
#define FILLB3 ((NEDGES / FEPT8 + 255) / 256)      // 391 fill blocks (8 edges/thread)
#define G96B ((NNODES + 127) / 128)                // 391 gemm96 blocks
#define NDROP4 ((NNODES * NHID / 4 + 255) / 256)   // 4688 drop0 blocks

// ---------- JAX Threefry-2x32 (Random123 20-round, matches jax._src.prng) ----------
__host__ __device__ inline void tf2x32(uint32_t k0, uint32_t k1, uint32_t x0, uint32_t x1,
                                       uint32_t& o0, uint32_t& o1) {
  uint32_t k2 = k0 ^ k1 ^ 0x1BD11BDAu;
#define TFROT(v, r) (((v) << (r)) | ((v) >> (32 - (r))))
#define TFR(r) { x0 += x1; x1 = TFROT(x1, r); x1 ^= x0; }
  x0 += k0; x1 += k1;
  TFR(13) TFR(15) TFR(26) TFR(6)
  x0 += k1; x1 += k2 + 1u;
  TFR(17) TFR(29) TFR(16) TFR(24)
  x0 += k2; x1 += k0 + 2u;
  TFR(13) TFR(15) TFR(26) TFR(6)
  x0 += k0; x1 += k1 + 3u;
  TFR(17) TFR(29) TFR(16) TFR(24)
  x0 += k1; x1 += k2 + 4u;
  TFR(13) TFR(15) TFR(26) TFR(6)
  x0 += k2; x1 += k0 + 5u;
  o0 = x0; o1 = x1;
#undef TFR
#undef TFROT
}

__device__ inline bool keep_bit(uint32_t k0, uint32_t k1, uint32_t j) {
  uint32_t o0, o1;
  tf2x32(k0, k1, 0u, j, o0, o1);
  return (((o0 ^ o1) >> 31) == 0u);   // uniform<0.5 <=> MSB==0
}

// ---------- pass 1: LDS histograms (blocks 0..400) + layer-0 dropout (rest) ----------
// inv_o is folded into csr weights at fill time, so drop0 is X = mask ? feat*2 : 0.
// The dst atomicAdd's return value is the edge's rank within (chunk,node) -> rank8.
// Block 0 zeroes the lookback flags for reduce_scan.
__global__ __launch_bounds__(256) void hist_drop_kernel(
    const int* __restrict__ src, const int* __restrict__ dst,
    uint32_t* __restrict__ slabD, uint32_t* __restrict__ slabS,
    uint8_t* __restrict__ rank8, uint32_t* __restrict__ flags,
    const float* __restrict__ h, float* __restrict__ X,
    uint32_t k0, uint32_t k1) {
  __shared__ uint32_t HD[RWORDS8];
  __shared__ uint32_t HS[RWORDS8];
  const int tid = threadIdx.x, b = blockIdx.x;
  if (b >= HISTBLKS) {
    // ---- drop0 branch: one float4 per thread ----
    int j = ((b - HISTBLKS) * 256 + tid) * 4;
    if (j < NNODES * NHID) {
      float4 hv = *(const float4*)(h + j);
      float4 o;
      o.x = keep_bit(k0, k1, (uint32_t)(j + 0)) ? hv.x * 2.0f : 0.0f;
      o.y = keep_bit(k0, k1, (uint32_t)(j + 1)) ? hv.y * 2.0f : 0.0f;
      o.z = keep_bit(k0, k1, (uint32_t)(j + 2)) ? hv.z * 2.0f : 0.0f;
      o.w = keep_bit(k0, k1, (uint32_t)(j + 3)) ? hv.w * 2.0f : 0.0f;
      *(float4*)(X + j) = o;
    }
    return;
  }
  // ---- hist branch ----
  if (b == 0 && tid < SCANB) flags[tid] = 0;
  const int c = b / NR, r = b - c * NR;
  const int e0 = c * EPB, e1 = e0 + EPB;
  const int nbase = r * RNODES;
  for (int w = tid; w < RWORDS8; w += 256) { HD[w] = 0; HS[w] = 0; }
  __syncthreads();
  int e = e0 + tid;
  for (; e + 768 < e1; e += 1024) {
    int d0 = dst[e] - nbase,       d1 = dst[e + 256] - nbase;
    int d2 = dst[e + 512] - nbase, d3 = dst[e + 768] - nbase;
    int s0 = src[e] - nbase,       s1 = src[e + 256] - nbase;
    int s2 = src[e + 512] - nbase, s3 = src[e + 768] - nbase;
    if ((unsigned)d0 < (unsigned)RNODES) {
      int sh = (d0 & 3) * 8;
      uint32_t old = atomicAdd(&HD[d0 >> 2], 1u << sh);
      rank8[e] = (uint8_t)((old >> sh) & 0xFFu);
    }
    if ((unsigned)d1 < (unsigned)RNODES) {
      int sh = (d1 & 3) * 8;
      uint32_t old = atomicAdd(&HD[d1 >> 2], 1u << sh);
      rank8[e + 256] = (uint8_t)((old >> sh) & 0xFFu);
    }
    if ((unsigned)d2 < (unsigned)RNODES) {
      int sh = (d2 & 3) * 8;
      uint32_t old = atomicAdd(&HD[d2 >> 2], 1u << sh);
      rank8[e + 512] = (uint8_t)((old >> sh) & 0xFFu);
    }
    if ((unsigned)d3 < (unsigned)RNODES) {
      int sh = (d3 & 3) * 8;
      uint32_t old = atomicAdd(&HD[d3 >> 2], 1u << sh);
      rank8[e + 768] = (uint8_t)((old >> sh) & 0xFFu);
    }
    if ((unsigned)s0 < (unsigned)RNODES) atomicAdd(&HS[s0 >> 2], 1u << ((s0 & 3) * 8));
    if ((unsigned)s1 < (unsigned)RNODES) atomicAdd(&HS[s1 >> 2], 1u << ((s1 & 3) * 8));
    if ((unsigned)s2 < (unsigned)RNODES) atomicAdd(&HS[s2 >> 2], 1u << ((s2 & 3) * 8));
    if ((unsigned)s3 < (unsigned)RNODES) atomicAdd(&HS[s3 >> 2], 1u << ((s3 & 3) * 8));
  }
  for (; e < e1; e += 256) {
    int d = dst[e] - nbase;
    if ((unsigned)d < (unsigned)RNODES) {
      int sh = (d & 3) * 8;
      uint32_t old = atomicAdd(&HD[d >> 2], 1u << sh);
      rank8[e] = (uint8_t)((old >> sh) & 0xFFu);
    }
    int s = src[e] - nbase;
    if ((unsigned)s < (unsigned)RNODES) atomicAdd(&HS[s >> 2], 1u << ((s & 3) * 8));
  }
  __syncthreads();
  uint32_t* dpD = slabD + (size_t)b * RWORDS8;
  uint32_t* dpS = slabS + (size_t)b * RWORDS8;
  for (int w = tid; w < RWORDS8; w += 256) { dpD[w] = HD[w]; dpS[w] = HS[w]; }
}

// ---------- fused reduce + rel-base + inv + full exclusive scan -> row_ptr ----------
// packed-byte running sums (per-node degree < 256 so no cross-byte carry).
// Decoupled lookback over 49 blocks (all co-resident): flags[b] = 0x80000000|total.
__global__ __launch_bounds__(256) void reduce_scan_kernel(
    const uint32_t* __restrict__ slabD, const uint32_t* __restrict__ slabS,
    float* __restrict__ inv_o, float* __restrict__ inv_i,
    uint32_t* __restrict__ rel8, int* __restrict__ row_ptr,
    uint32_t* __restrict__ flags) {
  __shared__ int lds[256];
  __shared__ int base_s;
  const int tid = threadIdx.x, b = blockIdx.x;
  const int gw = b * 256 + tid;
  uint32_t runD = 0, runS = 0;
  int n0 = 0;
  if (gw < NWORDS8) {
    int r = gw / RWORDS8, lw = gw - r * RWORDS8;
    n0 = r * RNODES + 4 * lw;
#pragma unroll 4
    for (int c = 0; c < NC; ++c) {
      rel8[(size_t)c * NWORDS8 + gw] = runD;
      runD += slabD[(size_t)(c * NR + r) * RWORDS8 + lw];
      runS += slabS[(size_t)(c * NR + r) * RWORDS8 + lw];
    }
  }
  const int d0 = runD & 0xFF, d1 = (runD >> 8) & 0xFF,
            d2 = (runD >> 16) & 0xFF, d3 = runD >> 24;
  const int tsum = d0 + d1 + d2 + d3;
  lds[tid] = tsum;
  __syncthreads();
  for (int off = 1; off < 256; off <<= 1) {
    int t = (tid >= off) ? lds[tid - off] : 0;
    __syncthreads();
    lds[tid] += t;
    __syncthreads();
  }
  const int incl = lds[tid];
  if (tid == 255) atomicExch(&flags[b], 0x80000000u | (uint32_t)lds[255]);
  if (tid < 64) {
    uint32_t part = 0;
    if (tid < b) {
      uint32_t v;
      do { v = atomicAdd(&flags[tid], 0u); } while (!(v & 0x80000000u));
      part = v & 0x7FFFFFFFu;
    }
#pragma unroll
    for (int off = 32; off > 0; off >>= 1)
      part += __shfl_down((unsigned)part, off, 64);
    if (tid == 0) base_s = (int)part;
  }
  __syncthreads();
  const int base = base_s;
  if (gw < NWORDS8) {
    int excl = base + incl - tsum;   // exclusive prefix for node n0
    *(int4*)(row_ptr + n0) = make_int4(excl, excl + d0, excl + d0 + d1, excl + d0 + d1 + d2);
    *(float4*)(inv_i + n0) = make_float4(
        rsqrtf(fmaxf((float)d0, 1.0f)), rsqrtf(fmaxf((float)d1, 1.0f)),
        rsqrtf(fmaxf((float)d2, 1.0f)), rsqrtf(fmaxf((float)d3, 1.0f)));
    int o0 = runS & 0xFF, o1 = (runS >> 8) & 0xFF, o2 = (runS >> 16) & 0xFF, o3 = runS >> 24;
    *(float4*)(inv_o + n0) = make_float4(
        rsqrtf(fmaxf((float)o0, 1.0f)), rsqrtf(fmaxf((float)o1, 1.0f)),
        rsqrtf(fmaxf((float)o2, 1.0f)), rsqrtf(fmaxf((float)o3, 1.0f)));
    if (gw == NWORDS8 - 1) row_ptr[NNODES] = NEDGES;
  }
}

// ---------- fused: gemm96 layer 0 (blocks 0..391) + streaming CSR fill (rest) ----------
// GEMM BLOCKS FIRST: in-order dispatch puts all 391 compute blocks across the
// CUs at t=0; the 391 fill blocks (8 edges/thread) trail into remaining slots.
// Total 782 blocks <= 1024 resident slots (36KB LDS, 4 blocks/CU) -> everything
// co-resident, fill's scatter latency hides under gemm's FMA work.
__global__ __launch_bounds__(256) void fill_gemm_kernel(
    const int* __restrict__ src, const int* __restrict__ dst, const float* __restrict__ ew,
    const uint8_t* __restrict__ rank8, const uint32_t* __restrict__ rel8,
    const int* __restrict__ row_ptr, const float* __restrict__ inv_o,
    uint32_t* __restrict__ csr,
    const float* __restrict__ X, const float* __restrict__ W, __half* __restrict__ Yh) {
  __shared__ float Wl[96 * 96];
  const int tid = threadIdx.x, b = blockIdx.x;
  if (b >= G96B) {
    // ---- fill branch: 8 edges/thread; payload = (src<<16)|fp16(w*inv_o[src]) ----
    int t = (b - G96B) * 256 + tid;
    int e = t * 8;
    if (e >= NEDGES) return;
    // EPB (8000) % 8 == 0 and e % 8 == 0 -> e..e+7 share one chunk
    const uint32_t* rel = rel8 + (size_t)(e / EPB) * NWORDS8;
    int4 dA = *(const int4*)(dst + e), dB = *(const int4*)(dst + e + 4);
    int4 sA = *(const int4*)(src + e), sB = *(const int4*)(src + e + 4);
    float4 wA = *(const float4*)(ew + e), wB = *(const float4*)(ew + e + 4);
    uint2 r8 = *(const uint2*)(rank8 + e);
#pragma unroll
    for (int k = 0; k < 8; ++k) {
      int d = (k < 4) ? (&dA.x)[k] : (&dB.x)[k - 4];
      int s = (k < 4) ? (&sA.x)[k] : (&sB.x)[k - 4];
      float w = ((k < 4) ? (&wA.x)[k] : (&wB.x)[k - 4]) * inv_o[s];
      int rk = (int)(((k < 4 ? r8.x : r8.y) >> ((k & 3) * 8)) & 0xFFu);
      int sh = (d & 3) * 8;
      int rel_v = (int)((rel[d >> 2] >> sh) & 0xFFu);
      int pos = row_ptr[d] + rel_v + rk;
      uint32_t v = ((uint32_t)s << 16) | (uint32_t)__half_as_ushort(__float2half_rn(w));
      if ((unsigned)pos < (unsigned)NEDGES) csr[pos] = v;
    }
    return;
  }
  // ---- gemm96 branch (layer 0) ----
  const int gb = b;
  {
    const float4* Wg = (const float4*)W;
    float4* Ws = (float4*)Wl;
#pragma unroll
    for (int i = 0; i < 9; ++i)
      Ws[tid + i * 256] = Wg[tid + i * 256];
  }
  __syncthreads();

  const int cg = tid & 7;
  const int rq = tid >> 3;
  const int row0 = gb * 128 + rq * 4;
  const int c0 = cg * 12;

  float acc[4][12];
#pragma unroll
  for (int r = 0; r < 4; ++r)
#pragma unroll
    for (int c = 0; c < 12; ++c) acc[r][c] = 0.f;

  const float* xr[4];
#pragma unroll
  for (int r = 0; r < 4; ++r) {
    int rr = row0 + r; if (rr > NNODES - 1) rr = NNODES - 1;
    xr[r] = X + (size_t)rr * 96;
  }

  for (int k = 0; k < 96; k += 4) {
    float4 x4[4];
#pragma unroll
    for (int r = 0; r < 4; ++r) x4[r] = *(const float4*)(xr[r] + k);
#pragma unroll
    for (int kk = 0; kk < 4; ++kk) {
      const float4* wp = (const float4*)(Wl + (k + kk) * 96 + c0);
      float4 w0 = wp[0], w1 = wp[1], w2 = wp[2];
      float xv[4] = { (&x4[0].x)[kk], (&x4[1].x)[kk], (&x4[2].x)[kk], (&x4[3].x)[kk] };
#pragma unroll
      for (int r = 0; r < 4; ++r) {
        acc[r][0]  += xv[r] * w0.x; acc[r][1]  += xv[r] * w0.y;
        acc[r][2]  += xv[r] * w0.z; acc[r][3]  += xv[r] * w0.w;
        acc[r][4]  += xv[r] * w1.x; acc[r][5]  += xv[r] * w1.y;
        acc[r][6]  += xv[r] * w1.z; acc[r][7]  += xv[r] * w1.w;
        acc[r][8]  += xv[r] * w2.x; acc[r][9]  += xv[r] * w2.y;
        acc[r][10] += xv[r] * w2.z; acc[r][11] += xv[r] * w2.w;
      }
    }
  }

#pragma unroll
  for (int r = 0; r < 4; ++r) {
    int rr = row0 + r;
    if (rr < NNODES) {
      __half2* hp = (__half2*)(Yh + (size_t)rr * 96 + c0);
#pragma unroll
      for (int c = 0; c < 6; ++c)
        hp[c] = __floats2half2_rn(acc[r][2 * c], acc[r][2 * c + 1]);
    }
  }
}

// ---------- GEMM96 (standalone, layer 1) ----------
__global__ __launch_bounds__(256) void gemm96_kernel(
    const float* __restrict__ X, const float* __restrict__ W, __half* __restrict__ Yh) {
  __shared__ float Wl[96 * 96];
  const int tid = threadIdx.x;
  {
    const float4* Wg = (const float4*)W;
    float4* Ws = (float4*)Wl;
#pragma unroll
    for (int i = 0; i < 9; ++i)
      Ws[tid + i * 256] = Wg[tid + i * 256];
  }
  __syncthreads();

  const int cg = tid & 7;
  const int rq = tid >> 3;
  const int row0 = blockIdx.x * 128 + rq * 4;
  const int c0 = cg * 12;

  float acc[4][12];
#pragma unroll
  for (int r = 0; r < 4; ++r)
#pragma unroll
    for (int c = 0; c < 12; ++c) acc[r][c] = 0.f;

  const float* xr[4];
#pragma unroll
  for (int r = 0; r < 4; ++r) {
    int rr = row0 + r; if (rr > NNODES - 1) rr = NNODES - 1;
    xr[r] = X + (size_t)rr * 96;
  }

  for (int k = 0; k < 96; k += 4) {
    float4 x4[4];
#pragma unroll
    for (int r = 0; r < 4; ++r) x4[r] = *(const float4*)(xr[r] + k);
#pragma unroll
    for (int kk = 0; kk < 4; ++kk) {
      const float4* wp = (const float4*)(Wl + (k + kk) * 96 + c0);
      float4 w0 = wp[0], w1 = wp[1], w2 = wp[2];
      float xv[4] = { (&x4[0].x)[kk], (&x4[1].x)[kk], (&x4[2].x)[kk], (&x4[3].x)[kk] };
#pragma unroll
      for (int r = 0; r < 4; ++r) {
        acc[r][0]  += xv[r] * w0.x; acc[r][1]  += xv[r] * w0.y;
        acc[r][2]  += xv[r] * w0.z; acc[r][3]  += xv[r] * w0.w;
        acc[r][4]  += xv[r] * w1.x; acc[r][5]  += xv[r] * w1.y;
        acc[r][6]  += xv[r] * w1.z; acc[r][7]  += xv[r] * w1.w;
        acc[r][8]  += xv[r] * w2.x; acc[r][9]  += xv[r] * w2.y;
        acc[r][10] += xv[r] * w2.z; acc[r][11] += xv[r] * w2.w;
      }
    }
  }

#pragma unroll
  for (int r = 0; r < 4; ++r) {
    int rr = row0 + r;
    if (rr < NNODES) {
      __half2* hp = (__half2*)(Yh + (size_t)rr * 96 + c0);
#pragma unroll
      for (int c = 0; c < 6; ++c)
        hp[c] = __floats2half2_rn(acc[r][2 * c], acc[r][2 * c + 1]);
    }
  }
}

// ---------- GEMM16: Y2h[N,16](fp16) = X[N,96] @ W[96,16], LDS-staged W ----------
__global__ __launch_bounds__(256) void gemm16_kernel(
    const float* __restrict__ X, const float* __restrict__ W, __half* __restrict__ Y2h) {
  __shared__ float Wl[96 * 16];
  const int tid = threadIdx.x;
  {
    const float4* Wg = (const float4*)W;
    float4* Ws = (float4*)Wl;
    for (int i = tid; i < 384; i += 256) Ws[i] = Wg[i];
  }
  __syncthreads();

  const int row0 = blockIdx.x * 512 + tid * 2;
  const float* xr[2];
#pragma unroll
  for (int r = 0; r < 2; ++r) {
    int rr = row0 + r; if (rr > NNODES - 1) rr = NNODES - 1;
    xr[r] = X + (size_t)rr * 96;
  }

  float acc[2][16];
#pragma unroll
  for (int r = 0; r < 2; ++r)
#pragma unroll
    for (int c = 0; c < 16; ++c) acc[r][c] = 0.f;

  for (int k = 0; k < 96; k += 4) {
    float4 x4[2];
#pragma unroll
    for (int r = 0; r < 2; ++r) x4[r] = *(const float4*)(xr[r] + k);
#pragma unroll
    for (int kk = 0; kk < 4; ++kk) {
      const float4* wp = (const float4*)(Wl + (k + kk) * 16);
      float4 w0 = wp[0], w1 = wp[1], w2 = wp[2], w3 = wp[3];
#pragma unroll
      for (int r = 0; r < 2; ++r) {
        float xv = (&x4[r].x)[kk];
        acc[r][0]  += xv * w0.x; acc[r][1]  += xv * w0.y;
        acc[r][2]  += xv * w0.z; acc[r][3]  += xv * w0.w;
        acc[r][4]  += xv * w1.x; acc[r][5]  += xv * w1.y;
        acc[r][6]  += xv * w1.z; acc[r][7]  += xv * w1.w;
        acc[r][8]  += xv * w2.x; acc[r][9]  += xv * w2.y;
        acc[r][10] += xv * w2.z; acc[r][11] += xv * w2.w;
        acc[r][12] += xv * w3.x; acc[r][13] += xv * w3.y;
        acc[r][14] += xv * w3.z; acc[r][15] += xv * w3.w;
      }
    }
  }

#pragma unroll
  for (int r = 0; r < 2; ++r) {
    int rr = row0 + r;
    if (rr < NNODES) {
      __half2* hp = (__half2*)(Y2h + (size_t)rr * 16);
#pragma unroll
      for (int c = 0; c < 8; ++c)
        hp[c] = __floats2half2_rn(acc[r][2 * c], acc[r][2 * c + 1]);
    }
  }
}

// accumulate one uint2 (4 fp16) into acc[0..3] with weight wt
#define ACC4(u0, wt) { \
  float2 g0 = __half22float2(*(__half2*)&u0.x); \
  float2 g1 = __half22float2(*(__half2*)&u0.y); \
  acc[0] += g0.x * wt; acc[1] += g0.y * wt; \
  acc[2] += g1.x * wt; acc[3] += g1.y * wt; }

// ---------- CSR gather (fp16 Y) + inv_in*bias + ReLU + dropout*2 ----------
// 24 threads/node, 4-dim (one uint2) chunks: 1.2M threads (proven best shape;
// TLP saturates here -- resident-thread cap is the binding constraint).
__global__ __launch_bounds__(256) void gather96_drop_kernel(
    const __half* __restrict__ Yh, const uint32_t* __restrict__ csr,
    const int* __restrict__ row_ptr, const float* __restrict__ inv_in,
    const float* __restrict__ bias,
    float* __restrict__ Xn, uint32_t k0, uint32_t k1) {
  int tid = blockIdx.x * 256 + threadIdx.x;
  int n = tid / 24;
  int q = tid - n * 24;        // 4-dim chunk within the 96-dim row
  if (n >= NNODES) return;
  int beg = row_ptr[n], end = row_ptr[n + 1];
  float acc[4];
#pragma unroll
  for (int i = 0; i < 4; ++i) acc[i] = 0.f;

  int p = beg;
  for (; p + 8 <= end; p += 8) {
    uint32_t pw[8];
#pragma unroll
    for (int i = 0; i < 8; ++i) pw[i] = csr[p + i];
    float wv[8];
    uint2 u[8];
#pragma unroll
    for (int i = 0; i < 8; ++i) {
      int s = (int)(pw[i] >> 16); if (s >= NNODES) s = 0;
      wv[i] = __half2float(__ushort_as_half((unsigned short)(pw[i] & 0xFFFFu)));
      u[i] = *(const uint2*)(Yh + (size_t)s * 96 + q * 4);
    }
#pragma unroll
    for (int i = 0; i < 8; ++i) { ACC4(u[i], wv[i]) }
  }
  for (; p + 2 <= end; p += 2) {
    uint32_t pa = csr[p], pb = csr[p + 1];
    int s0 = pa >> 16, s1 = pb >> 16;
    if (s0 >= NNODES) s0 = 0;
    if (s1 >= NNODES) s1 = 0;
    float w0 = __half2float(__ushort_as_half((unsigned short)(pa & 0xFFFFu)));
    float w1 = __half2float(__ushort_as_half((unsigned short)(pb & 0xFFFFu)));
    uint2 a0 = *(const uint2*)(Yh + (size_t)s0 * 96 + q * 4);
    uint2 b0 = *(const uint2*)(Yh + (size_t)s1 * 96 + q * 4);
    ACC4(a0, w0)
    ACC4(b0, w1)
  }
  if (p < end) {
    uint32_t pa = csr[p];
    int s0 = pa >> 16;
    if (s0 >= NNODES) s0 = 0;
    float w0 = __half2float(__ushort_as_half((unsigned short)(pa & 0xFFFFu)));
    uint2 a0 = *(const uint2*)(Yh + (size_t)s0 * 96 + q * 4);
    ACC4(a0, w0)
  }

  float iv = inv_in[n];
  const float* bp = bias + q * 4;
  float o[4];
#pragma unroll
  for (int i = 0; i < 4; ++i)
    o[i] = fmaxf(acc[i] * iv + bp[i], 0.f) * 2.0f;   // dropout 1/(1-p) only
  uint32_t jb = (uint32_t)(n * 96 + q * 4);
#pragma unroll
  for (int i = 0; i < 4; ++i)
    o[i] = keep_bit(k0, k1, jb + i) ? o[i] : 0.f;
  float* xp = Xn + (size_t)n * 96 + q * 4;
  *(float4*)xp = make_float4(o[0], o[1], o[2], o[3]);
}

// ---------- layer 2: CSR gather (fp16 Y2) + bias + log_softmax ----------
// 4 threads/node (4 dims each, one uint2/edge); softmax max/sum combined across
// the 4-lane group via shfl_xor(1)+shfl_xor(2).
__global__ __launch_bounds__(256) void gather16_lsm_kernel(
    const __half* __restrict__ Y2h, const uint32_t* __restrict__ csr,
    const int* __restrict__ row_ptr, const float* __restrict__ inv_in,
    const float* __restrict__ b2, float* __restrict__ out) {
  int t = blockIdx.x * 256 + threadIdx.x;
  int n = t >> 2;
  int q = t & 3;              // 4-dim quarter of the 16-dim row
  if (n >= NNODES) return;
  int beg = row_ptr[n], end = row_ptr[n + 1];
  float acc[4];
#pragma unroll
  for (int i = 0; i < 4; ++i) acc[i] = 0.f;

  int p = beg;
  for (; p + 4 <= end; p += 4) {
    uint32_t pa = csr[p], pb = csr[p + 1], pc = csr[p + 2], pd = csr[p + 3];
    int sa = pa >> 16, sb = pb >> 16, sc_ = pc >> 16, sd = pd >> 16;
    if (sa >= NNODES) sa = 0;
    if (sb >= NNODES) sb = 0;
    if (sc_ >= NNODES) sc_ = 0;
    if (sd >= NNODES) sd = 0;
    float wa = __half2float(__ushort_as_half((unsigned short)(pa & 0xFFFFu)));
    float wb = __half2float(__ushort_as_half((unsigned short)(pb & 0xFFFFu)));
    float wc = __half2float(__ushort_as_half((unsigned short)(pc & 0xFFFFu)));
    float wd = __half2float(__ushort_as_half((unsigned short)(pd & 0xFFFFu)));
    uint2 a0 = *(const uint2*)(Y2h + (size_t)sa * 16 + q * 4);
    uint2 b0 = *(const uint2*)(Y2h + (size_t)sb * 16 + q * 4);
    uint2 c0 = *(const uint2*)(Y2h + (size_t)sc_ * 16 + q * 4);
    uint2 d0 = *(const uint2*)(Y2h + (size_t)sd * 16 + q * 4);
    ACC4(a0, wa) ACC4(b0, wb) ACC4(c0, wc) ACC4(d0, wd)
  }
  for (; p + 2 <= end; p += 2) {
    uint32_t pa = csr[p], pb = csr[p + 1];
    int sa = pa >> 16, sb = pb >> 16;
    if (sa >= NNODES) sa = 0;
    if (sb >= NNODES) sb = 0;
    float wa = __half2float(__ushort_as_half((unsigned short)(pa & 0xFFFFu)));
    float wb = __half2float(__ushort_as_half((unsigned short)(pb & 0xFFFFu)));
    uint2 a0 = *(const uint2*)(Y2h + (size_t)sa * 16 + q * 4);
    uint2 b0 = *(const uint2*)(Y2h + (size_t)sb * 16 + q * 4);
    ACC4(a0, wa) ACC4(b0, wb)
  }
  if (p < end) {
    uint32_t pa = csr[p];
    int sa = pa >> 16;
    if (sa >= NNODES) sa = 0;
    float wa = __half2float(__ushort_as_half((unsigned short)(pa & 0xFFFFu)));
    uint2 a0 = *(const uint2*)(Y2h + (size_t)sa * 16 + q * 4);
    ACC4(a0, wa)
  }

  float iv = inv_in[n];
  float v[4];
#pragma unroll
  for (int i = 0; i < 4; ++i) v[i] = acc[i] * iv + b2[q * 4 + i];
  float m = v[0];
#pragma unroll
  for (int i = 1; i < 4; i++) m = fmaxf(m, v[i]);
  m = fmaxf(m, __shfl_xor(m, 1));       // 4-lane group shares node n
  m = fmaxf(m, __shfl_xor(m, 2));
  float s = 0.f;
#pragma unroll
  for (int i = 0; i < 4; i++) s += expf(v[i] - m);
  s += __shfl_xor(s, 1);
  s += __shfl_xor(s, 2);
  float ls = logf(s);
  float* orow = out + (size_t)n * 16 + q * 4;
  *(float4*)orow = make_float4(v[0] - m - ls, v[1] - m - ls, v[2] - m - ls, v[3] - m - ls);
}

extern "C" void kernel_launch(void* const* d_in, const int* in_sizes, int n_in,
                              void* d_out, int out_size, void* d_ws, size_t ws_size,
                              hipStream_t stream) {
  const float* feat = (const float*)d_in[0];
  const float* ew   = (const float*)d_in[1];
  const int*   src  = (const int*)d_in[2];
  const int*   dst  = (const int*)d_in[3];
  const float* W0   = (const float*)d_in[4];
  const float* b0   = (const float*)d_in[5];
  const float* W1   = (const float*)d_in[6];
  const float* b1   = (const float*)d_in[7];
  const float* W2   = (const float*)d_in[8];
  const float* b2   = (const float*)d_in[9];
  float* out = (float*)d_out;

  char* base = (char*)d_ws;
  size_t off = 0;
  auto take = [&](size_t nbytes) {
    void* q = base + off;
    off += (nbytes + 255) & ~(size_t)255;
    return q;
  };
  uint32_t* flags   = (uint32_t*)take((size_t)SCANB * 4);
  int*      row_ptr = (int*)take((size_t)(NNODES + 1) * 4);
  float*    inv_o   = (float*)take((size_t)NNODES * 4);
  float*    inv_i   = (float*)take((size_t)NNODES * 4);
  uint32_t* slabD   = (uint32_t*)take((size_t)NC * NR * RWORDS8 * 4);  // 5 MB
  uint32_t* slabS   = (uint32_t*)take((size_t)NC * NR * RWORDS8 * 4);  // 5 MB
  uint32_t* rel8    = (uint32_t*)take((size_t)NC * NWORDS8 * 4);       // 5 MB
  uint8_t*  rank8   = (uint8_t*)take((size_t)NEDGES);                  // 0.8 MB
  uint32_t* csr     = (uint32_t*)take((size_t)NEDGES * 4);
  float*    X       = (float*)take((size_t)NNODES * NHID * 4);
  __half*   Yh      = (__half*)take((size_t)NNODES * NHID * 2);
  __half*   Y2h     = (__half*)take((size_t)NNODES * NCLS * 2);
  (void)ws_size; (void)in_sizes; (void)n_in; (void)out_size;

  uint32_t k[3][2];
  for (uint32_t i = 0; i < 3; i++) tf2x32(0u, 42u, 0u, i, k[i][0], k[i][1]);

  // graph build: hist (+drop0 co-scheduled), scan, then gemm96-L0||fill fused
  hist_drop_kernel<<<HISTBLKS + NDROP4, 256, 0, stream>>>(
      src, dst, slabD, slabS, rank8, flags, feat, X, k[0][0], k[0][1]);
  reduce_scan_kernel<<<SCANB, 256, 0, stream>>>(slabD, slabS, inv_o, inv_i, rel8, row_ptr, flags);
  fill_gemm_kernel<<<G96B + FILLB3, 256, 0, stream>>>(
      src, dst, ew, rank8, rel8, row_ptr, inv_o, csr, X, W0, Yh);

  const int G16  = (NNODES + 511) / 512;        // 98
  const int GGD  = (NNODES * 24 + 255) / 256;   // 4688
  const int GLSM = (NNODES * 4 + 255) / 256;    // 782

  // layer 0 gather
  gather96_drop_kernel<<<GGD, 256, 0, stream>>>(Yh, csr, row_ptr, inv_i, b0, X, k[1][0], k[1][1]);
  // layer 1
  gemm96_kernel<<<G96B, 256, 0, stream>>>(X, W1, Yh);
  gather96_drop_kernel<<<GGD, 256, 0, stream>>>(Yh, csr, row_ptr, inv_i, b1, X, k[2][0], k[2][1]);
  // layer 2
  gemm16_kernel<<<G16, 256, 0, stream>>>(X, W2, Y2h);
  gather16_lsm_kernel<<<GLSM, 256, 0, stream>>>(Y2h, csr, row_ptr, inv_i, b2, out);
}